// Round 5
// baseline (229.589 us; speedup 1.0000x reference)
//
#include <hip/hip_runtime.h>
#include <hip/hip_bf16.h>

// Problem constants
#define NB   128     // frames
#define NP   4096    // points per frame
#define NGRP 16
#define C3   512

typedef __bf16 bf16x8 __attribute__((ext_vector_type(8)));
typedef __bf16 bf16x4 __attribute__((ext_vector_type(4)));
typedef float  f32x4  __attribute__((ext_vector_type(4)));

// ws layout (bytes) — all weights in MFMA A-fragment chunk order:
// chunk c holds A[m=l15][k=quad*8+j] as elem c*512 + lane*8 + j
#define WS_W1F_G 0        // 4 chunks (64ch x K32, k>=4 zero)
#define WS_W1F_L 4096
#define WS_W2F_G 8192     // 16 chunks (128ch x K64): c = mi*2 + ks
#define WS_W2F_L 24576
#define WS_W3F_G 40960    // 128 chunks (512ch x K128): c = (ch>>4)*4 + (k>>5)
#define WS_W3F_L 172032
#define WS_GMAX  303104   // [16][512] f32 (end 335872)

__global__ __launch_bounds__(256) void prep_kernel(
    const float* __restrict__ Wg1, const float* __restrict__ Wg2, const float* __restrict__ Wg3,
    const float* __restrict__ Wl1, const float* __restrict__ Wl2, const float* __restrict__ Wl3,
    char* __restrict__ ws) {
    const int t = blockIdx.x, tid = threadIdx.x;
    if (t == 36) {   // W1 frags (both branches) + gmax zero
        float* gmax = (float*)(ws + WS_GMAX);
        #pragma unroll
        for (int k = 0; k < 32; ++k) gmax[k * 256 + tid] = 0.0f;
        int c = tid >> 6, lane = tid & 63;
        int ch = c * 16 + (lane & 15);
        int kb = (lane >> 4) * 8;
        bf16x8 pg, pl;
        #pragma unroll
        for (int j = 0; j < 8; ++j) {
            int k = kb + j;
            pg[j] = (k < 4) ? (__bf16)Wg1[k * 64 + ch] : (__bf16)0.0f;
            pl[j] = (k < 4) ? (__bf16)Wl1[k * 64 + ch] : (__bf16)0.0f;
        }
        *(bf16x8*)((__bf16*)(ws + WS_W1F_G) + c * 512 + lane * 8) = pg;
        *(bf16x8*)((__bf16*)(ws + WS_W1F_L) + c * 512 + lane * 8) = pl;
        return;
    }
    // W2/W3 transpose-to-fragment tiles via LDS (coalesced both sides)
    __shared__ float tile[64][65];
    const float* src; __bf16* dst; int cBase, mMul, srcStride;
    if (t < 32) {       // W3 [128k][512ch]: tiles 64x64, (tk 0..1, tc 0..7) per branch
        int branch = t >> 4, rem = t & 15;
        int tk = rem >> 3, tc = rem & 7;
        src = (branch ? Wl3 : Wg3) + (size_t)(tk * 64) * 512 + tc * 64;
        dst = (__bf16*)(ws + (branch ? WS_W3F_L : WS_W3F_G));
        cBase = tc * 16 + tk * 2; mMul = 4; srcStride = 512;
    } else {            // W2 [64k][128ch]: tiles 64x64, tc 0..1 per branch
        int u = t - 32; int branch = u >> 1, tc = u & 1;
        src = (branch ? Wl2 : Wg2) + tc * 64;
        dst = (__bf16*)(ws + (branch ? WS_W2F_L : WS_W2F_G));
        cBase = tc * 8; mMul = 2; srcStride = 128;
    }
    {
        int r0 = tid >> 6, cl = tid & 63;
        #pragma unroll
        for (int p = 0; p < 16; ++p)
            tile[p * 4 + r0][cl] = src[(size_t)(p * 4 + r0) * srcStride + cl];
    }
    __syncthreads();
    int lane = tid & 63, l15 = lane & 15, q = lane >> 4;
    #pragma unroll
    for (int cc = 0; cc < 2; ++cc) {
        int pair = (tid >> 6) * 2 + cc;     // (mi,ks) 0..7
        int mi = pair >> 1, ks = pair & 1;
        bf16x8 pk;
        #pragma unroll
        for (int j = 0; j < 8; ++j) pk[j] = (__bf16)tile[ks * 32 + q * 8 + j][mi * 16 + l15];
        *(bf16x8*)(dst + (cBase + mi * mMul + ks) * 512 + lane * 8) = pk;
    }
}

// Grid (128 frames, 2 branches) = 256 blocks = 1/CU. 8 waves. Block owns a
// whole frame: 32 macros of 128 pts. Round-0 135us structure (double-buffered
// h2f, ONE barrier/macro, stages A/B/C pipelined in the ni loop) plus:
//  - runtime SGPR de-phasing: waves 0-3 stage at ni=2/4/6, waves 4-7 (their
//    SIMD partners) at ni=1/3/5 -> on every SIMD one wave is in a pure
//    16-MFMA slot while the other runs its VALU/LDS stage (m114: MFMA+VALU
//    waves co-schedule). Stage C never lands at ni=7 (R4's tail mistake).
//    Single body, wave-uniform scalar guards — no template duplication
//    (R4's +20 VGPR/spill mistake).
//  - x prefetch 2 macros deep (+3 VGPR) so stage A at ni=1 is covered.
//  - h1s stride 72 (bank stride 4 mod 32; conflicts -30%, R4-verified).
//  - no setprio.
__global__ __launch_bounds__(512, 2) void main_kernel(
    const float* __restrict__ pc, const float* __restrict__ tt, const int* __restrict__ idx,
    const float* __restrict__ bg1, const float* __restrict__ bg2, const float* __restrict__ bg3,
    const float* __restrict__ bl1, const float* __restrict__ bl2, const float* __restrict__ bl3,
    float* __restrict__ out, char* __restrict__ ws) {
    __shared__ __align__(16) char smem[100864];
    __bf16* h2f = (__bf16*)smem;               // 2 x 16384 elems (65536 B)
    __bf16* w2f = (__bf16*)(smem + 65536);     // 8192 elems (16384 B)
    __bf16* h1s = (__bf16*)(smem + 81920);     // 8 waves x [16pt][72] (18432 B)
    float*  b2s = (float*)(smem + 100352);     // 128 f32 (512 B)

    const int tid = threadIdx.x, lane = tid & 63, wave = tid >> 6;
    const int quad = lane >> 4, l15 = lane & 15;
    const int branch = blockIdx.y, frame = blockIdx.x;

    const __bf16* w1g = (const __bf16*)(ws + (branch ? WS_W1F_L : WS_W1F_G));
    const __bf16* w2g = (const __bf16*)(ws + (branch ? WS_W2F_L : WS_W2F_G));
    const __bf16* w3g = (const __bf16*)(ws + (branch ? WS_W3F_L : WS_W3F_G));
    const float* b1 = branch ? bl1 : bg1;
    const float* b2 = branch ? bl2 : bg2;
    const float* b3 = branch ? bl3 : bg3;

    // stage W2 frags + b2 into LDS
    for (int i = tid; i < 1024; i += 512) ((f32x4*)w2f)[i] = ((const f32x4*)w2g)[i];
    if (tid < 128) b2s[tid] = b2[tid];

    // resident frags: W1 (16 VGPR), W3 slice (64 VGPR)
    bf16x8 a1[4];
    #pragma unroll
    for (int mi = 0; mi < 4; ++mi) a1[mi] = *(const bf16x8*)(w1g + mi * 512 + lane * 8);
    bf16x8 aw[4][4];
    #pragma unroll
    for (int mi = 0; mi < 4; ++mi)
        #pragma unroll
        for (int ks = 0; ks < 4; ++ks)
            aw[mi][ks] = *(const bf16x8*)(w3g + (wave * 16 + mi * 4 + ks) * 512 + lane * 8);

    float b1r[4][4];
    #pragma unroll
    for (int mi = 0; mi < 4; ++mi)
        #pragma unroll
        for (int r = 0; r < 4; ++r) b1r[mi][r] = b1[mi * 16 + quad * 4 + r];

    const float tval = tt[frame];
    const f32x4 zf = {0.0f, 0.0f, 0.0f, 0.0f};
    f32x4 runmax[4];
    #pragma unroll
    for (int mi = 0; mi < 4; ++mi) runmax[mi] = (f32x4){-1e30f, -1e30f, -1e30f, -1e30f};

    const float* pcx = pc + (size_t)frame * 3 * NP;
    __bf16* hs = h1s + wave * 1152;      // private [16][72] scratch
    const int pw = wave * 16 + l15;      // this wave's point (col l15) in a macro

    // de-phased stage slots: SIMD partner waves (w, w+4) offset by one ni-group
    const int sA = (wave & 4) ? 1 : 2;
    const int sB = sA + 2;
    const int sC = sA + 4;

    // x for macro 0 (used now) and macro 1 (stage A of macro 0)
    float xx = pcx[pw], xy = pcx[NP + pw], xz = pcx[2 * NP + pw];
    float cx = pcx[128 + pw], cy = pcx[NP + 128 + pw], cz = pcx[2 * NP + 128 + pw];

    __syncthreads();   // w2f/b2s ready

    // ---- prologue: P1(0) -> buf 0
    {
        bf16x8 xb;
        #pragma unroll
        for (int j = 0; j < 8; ++j) xb[j] = (__bf16)0.0f;
        if (quad == 0) { xb[0] = (__bf16)xx; xb[1] = (__bf16)xy; xb[2] = (__bf16)xz; xb[3] = (__bf16)tval; }
        #pragma unroll
        for (int mi = 0; mi < 4; ++mi) {
            f32x4 c = __builtin_amdgcn_mfma_f32_16x16x32_bf16(a1[mi], xb, zf, 0, 0, 0);
            bf16x4 pk;
            #pragma unroll
            for (int r = 0; r < 4; ++r) pk[r] = (__bf16)fmaxf(c[r] + b1r[mi][r], 0.0f);
            *(bf16x4*)(hs + l15 * 72 + mi * 16 + quad * 4) = pk;
        }
        bf16x8 hbf0 = *(const bf16x8*)(hs + l15 * 72 + quad * 8);
        bf16x8 hbf1 = *(const bf16x8*)(hs + l15 * 72 + 32 + quad * 8);
        #pragma unroll
        for (int mi = 0; mi < 8; ++mi) {
            bf16x8 a20 = *(const bf16x8*)(w2f + (mi * 2) * 512 + lane * 8);
            bf16x8 a21 = *(const bf16x8*)(w2f + (mi * 2 + 1) * 512 + lane * 8);
            f32x4 c = __builtin_amdgcn_mfma_f32_16x16x32_bf16(a20, hbf0, zf, 0, 0, 0);
            c = __builtin_amdgcn_mfma_f32_16x16x32_bf16(a21, hbf1, c, 0, 0, 0);
            f32x4 bb = *(const f32x4*)(b2s + mi * 16 + quad * 4);
            bf16x4 pk;
            #pragma unroll
            for (int r = 0; r < 4; ++r) pk[r] = (__bf16)fmaxf(c[r] + bb[r], 0.0f);
            const int c0 = mi * 16 + quad * 4;
            *(bf16x4*)(h2f + ((wave * 4 + (c0 >> 5)) * 4 + ((c0 >> 3) & 3)) * 128 + l15 * 8 + (c0 & 7)) = pk;
        }
    }

    for (int m = 0; m < 32; ++m) {
        __syncthreads();   // h2f buf[m&1] ready (prologue or previous stage C)
        const __bf16* hb = h2f + (m & 1) * 16384;
        __bf16* hbn = h2f + ((m + 1) & 1) * 16384;
        const bool more = (m < 31);
        // prefetch x of macro m+2 (consumed by stage A of macro m+1):
        // a full macro (~6k cyc) of latency cover even for stage A at ni=1.
        float nx = 0.f, ny = 0.f, nz = 0.f;
        if (m < 30) {
            const int p = (m + 2) * 128 + pw;
            nx = pcx[p]; ny = pcx[NP + p]; nz = pcx[2 * NP + p];
        }
        bf16x8 hbf0, hbf1;
        bf16x8 bh0[4], bh1[4];
        #pragma unroll
        for (int ks = 0; ks < 4; ++ks) bh0[ks] = *(const bf16x8*)(hb + ks * 512 + lane * 8);
        #pragma unroll
        for (int ni = 0; ni < 8; ++ni) {
            bf16x8* cur = (ni & 1) ? bh1 : bh0;
            bf16x8* nxt = (ni & 1) ? bh0 : bh1;
            if (ni < 7) {
                #pragma unroll
                for (int ks = 0; ks < 4; ++ks)
                    nxt[ks] = *(const bf16x8*)(hb + ((ni + 1) * 4 + ks) * 512 + lane * 8);
            }
            f32x4 acc[4];
            #pragma unroll
            for (int ks = 0; ks < 4; ++ks)
                #pragma unroll
                for (int mi = 0; mi < 4; ++mi)
                    acc[mi] = __builtin_amdgcn_mfma_f32_16x16x32_bf16(
                        aw[mi][ks], cur[ks], ks ? acc[mi] : zf, 0, 0, 0);
            #pragma unroll
            for (int mi = 0; mi < 4; ++mi)
                #pragma unroll
                for (int r = 0; r < 4; ++r)
                    runmax[mi][r] = fmaxf(runmax[mi][r], acc[mi][r]);

            if (more && ni == sA) {   // P1 stage A: L1 of macro m+1, private scratch
                bf16x8 xb;
                #pragma unroll
                for (int j = 0; j < 8; ++j) xb[j] = (__bf16)0.0f;
                if (quad == 0) { xb[0] = (__bf16)cx; xb[1] = (__bf16)cy; xb[2] = (__bf16)cz; xb[3] = (__bf16)tval; }
                #pragma unroll
                for (int mi = 0; mi < 4; ++mi) {
                    f32x4 c = __builtin_amdgcn_mfma_f32_16x16x32_bf16(a1[mi], xb, zf, 0, 0, 0);
                    bf16x4 pk;
                    #pragma unroll
                    for (int r = 0; r < 4; ++r) pk[r] = (__bf16)fmaxf(c[r] + b1r[mi][r], 0.0f);
                    *(bf16x4*)(hs + l15 * 72 + mi * 16 + quad * 4) = pk;
                }
            }
            if (more && ni == sB) {   // stage B: C->B transform readback
                hbf0 = *(const bf16x8*)(hs + l15 * 72 + quad * 8);
                hbf1 = *(const bf16x8*)(hs + l15 * 72 + 32 + quad * 8);
            }
            if (more && ni == sC) {   // stage C: L2 -> write next h2f buffer
                #pragma unroll
                for (int mi = 0; mi < 8; ++mi) {
                    bf16x8 a20 = *(const bf16x8*)(w2f + (mi * 2) * 512 + lane * 8);
                    bf16x8 a21 = *(const bf16x8*)(w2f + (mi * 2 + 1) * 512 + lane * 8);
                    f32x4 c = __builtin_amdgcn_mfma_f32_16x16x32_bf16(a20, hbf0, zf, 0, 0, 0);
                    c = __builtin_amdgcn_mfma_f32_16x16x32_bf16(a21, hbf1, c, 0, 0, 0);
                    f32x4 bb = *(const f32x4*)(b2s + mi * 16 + quad * 4);
                    bf16x4 pk;
                    #pragma unroll
                    for (int r = 0; r < 4; ++r) pk[r] = (__bf16)fmaxf(c[r] + bb[r], 0.0f);
                    const int c0 = mi * 16 + quad * 4;
                    *(bf16x4*)(hbn + ((wave * 4 + (c0 >> 5)) * 4 + ((c0 >> 3) & 3)) * 128 + l15 * 8 + (c0 & 7)) = pk;
                }
            }
        }
        cx = nx; cy = ny; cz = nz;
    }

    // ---- finalize: fold 16 point-columns, bias3+relu, store/atomic
    const int g = idx[frame];
    float* gmax = (float*)(ws + WS_GMAX);
    #pragma unroll
    for (int mi = 0; mi < 4; ++mi) {
        f32x4 v = runmax[mi];
        #pragma unroll
        for (int d = 1; d < 16; d <<= 1) {
            #pragma unroll
            for (int r = 0; r < 4; ++r) v[r] = fmaxf(v[r], __shfl_xor(v[r], d));
        }
        if (l15 == 0) {
            #pragma unroll
            for (int r = 0; r < 4; ++r) {
                const int ch = wave * 64 + mi * 16 + quad * 4 + r;
                const float fv = fmaxf(v[r] + b3[ch], 0.0f);
                if (branch == 0)
                    atomicMax((unsigned*)(gmax + g * C3 + ch), __float_as_uint(fv)); // relu>=0
                else
                    out[(size_t)frame * (2 * C3) + C3 + ch] = fv;  // block owns whole frame
            }
        }
    }
}

__global__ void gather_kernel(const int* __restrict__ idx, const char* __restrict__ ws,
                              const float* __restrict__ pc, float* __restrict__ out) {
    int i = blockIdx.x * blockDim.x + threadIdx.x;   // 0..65535
    int b = i >> 9, ch = i & 511;
    const float* gmax = (const float*)(ws + WS_GMAX);
    out[b * (2 * C3) + ch] = gmax[idx[b] * C3 + ch];
    // pc passthrough (off the prep->main critical path): 393216 float4
    const f32x4* src = (const f32x4*)pc;
    f32x4* dst = (f32x4*)(out + NB * 2 * C3);
    #pragma unroll
    for (int j = 0; j < 6; ++j) dst[i + j * 65536] = src[i + j * 65536];
}

extern "C" void kernel_launch(void* const* d_in, const int* in_sizes, int n_in,
                              void* d_out, int out_size, void* d_ws, size_t ws_size,
                              hipStream_t stream) {
    const float* pc  = (const float*)d_in[0];
    const float* tt  = (const float*)d_in[1];
    const int*   idx = (const int*)d_in[2];
    const float* Wg1 = (const float*)d_in[3];  const float* bg1 = (const float*)d_in[4];
    const float* Wg2 = (const float*)d_in[5];  const float* bg2 = (const float*)d_in[6];
    const float* Wg3 = (const float*)d_in[7];  const float* bg3 = (const float*)d_in[8];
    const float* Wl1 = (const float*)d_in[9];  const float* bl1 = (const float*)d_in[10];
    const float* Wl2 = (const float*)d_in[11]; const float* bl2 = (const float*)d_in[12];
    const float* Wl3 = (const float*)d_in[13]; const float* bl3 = (const float*)d_in[14];
    float* out = (float*)d_out;
    char*  ws  = (char*)d_ws;

    // prep: weight frag layout (LDS transpose), gmax zero
    prep_kernel<<<37, 256, 0, stream>>>(Wg1, Wg2, Wg3, Wl1, Wl2, Wl3, ws);
    // main: 128 frames x 2 branches = 256 blocks = 1 per CU
    main_kernel<<<dim3(128, 2), 512, 0, stream>>>(pc, tt, idx, bg1, bg2, bg3,
                                                  bl1, bl2, bl3, out, ws);
    gather_kernel<<<256, 256, 0, stream>>>(idx, ws, pc, out);
}

// Round 6
// 203.165 us; speedup vs baseline: 1.1301x; 1.1301x over previous
//
#include <hip/hip_runtime.h>
#include <hip/hip_bf16.h>

// Problem constants
#define NB   128     // frames
#define NP   4096    // points per frame
#define NGRP 16
#define C3   512

typedef __bf16 bf16x8 __attribute__((ext_vector_type(8)));
typedef __bf16 bf16x4 __attribute__((ext_vector_type(4)));
typedef float  f32x4  __attribute__((ext_vector_type(4)));

// ws layout (bytes) — all weights in MFMA A-fragment chunk order:
// chunk c holds A[m=l15][k=quad*8+j] as elem c*512 + lane*8 + j
#define WS_W1F_G 0        // 4 chunks (64ch x K32, k>=4 zero)
#define WS_W1F_L 4096
#define WS_W2F_G 8192     // 16 chunks (128ch x K64): c = mi*2 + ks
#define WS_W2F_L 24576
#define WS_W3F_G 40960    // 128 chunks (512ch x K128): c = (ch>>4)*4 + (k>>5)
#define WS_W3F_L 172032
#define WS_GMAX  303104   // [16][512] f32 (end 335872)

__global__ __launch_bounds__(256) void prep_kernel(
    const float* __restrict__ Wg1, const float* __restrict__ Wg2, const float* __restrict__ Wg3,
    const float* __restrict__ Wl1, const float* __restrict__ Wl2, const float* __restrict__ Wl3,
    char* __restrict__ ws) {
    const int t = blockIdx.x, tid = threadIdx.x;
    if (t == 36) {   // W1 frags (both branches) + gmax zero
        float* gmax = (float*)(ws + WS_GMAX);
        #pragma unroll
        for (int k = 0; k < 32; ++k) gmax[k * 256 + tid] = 0.0f;
        int c = tid >> 6, lane = tid & 63;
        int ch = c * 16 + (lane & 15);
        int kb = (lane >> 4) * 8;
        bf16x8 pg, pl;
        #pragma unroll
        for (int j = 0; j < 8; ++j) {
            int k = kb + j;
            pg[j] = (k < 4) ? (__bf16)Wg1[k * 64 + ch] : (__bf16)0.0f;
            pl[j] = (k < 4) ? (__bf16)Wl1[k * 64 + ch] : (__bf16)0.0f;
        }
        *(bf16x8*)((__bf16*)(ws + WS_W1F_G) + c * 512 + lane * 8) = pg;
        *(bf16x8*)((__bf16*)(ws + WS_W1F_L) + c * 512 + lane * 8) = pl;
        return;
    }
    // W2/W3 transpose-to-fragment tiles via LDS (coalesced both sides)
    __shared__ float tile[64][65];
    const float* src; __bf16* dst; int cBase, mMul, srcStride;
    if (t < 32) {       // W3 [128k][512ch]: tiles 64x64, (tk 0..1, tc 0..7) per branch
        int branch = t >> 4, rem = t & 15;
        int tk = rem >> 3, tc = rem & 7;
        src = (branch ? Wl3 : Wg3) + (size_t)(tk * 64) * 512 + tc * 64;
        dst = (__bf16*)(ws + (branch ? WS_W3F_L : WS_W3F_G));
        cBase = tc * 16 + tk * 2; mMul = 4; srcStride = 512;
    } else {            // W2 [64k][128ch]: tiles 64x64, tc 0..1 per branch
        int u = t - 32; int branch = u >> 1, tc = u & 1;
        src = (branch ? Wl2 : Wg2) + tc * 64;
        dst = (__bf16*)(ws + (branch ? WS_W2F_L : WS_W2F_G));
        cBase = tc * 8; mMul = 2; srcStride = 128;
    }
    {
        int r0 = tid >> 6, cl = tid & 63;
        #pragma unroll
        for (int p = 0; p < 16; ++p)
            tile[p * 4 + r0][cl] = src[(size_t)(p * 4 + r0) * srcStride + cl];
    }
    __syncthreads();
    int lane = tid & 63, l15 = lane & 15, q = lane >> 4;
    #pragma unroll
    for (int cc = 0; cc < 2; ++cc) {
        int pair = (tid >> 6) * 2 + cc;     // (mi,ks) 0..7
        int mi = pair >> 1, ks = pair & 1;
        bf16x8 pk;
        #pragma unroll
        for (int j = 0; j < 8; ++j) pk[j] = (__bf16)tile[ks * 32 + q * 8 + j][mi * 16 + l15];
        *(bf16x8*)(dst + (cBase + mi * mMul + ks) * 512 + lane * 8) = pk;
    }
}

// Grid (128 frames, 2 branches) = 256 blocks = 1/CU. 8 waves. Block owns a
// whole frame: 32 macros of 128 pts. Round-0 135us structure restored EXACTLY
// (hardcoded stage slots ni=2/4/6, single-macro x prefetch, double-buffered
// h2f, ONE barrier/macro) — the 108-VGPR no-spill configuration. Only
// register-neutral deltas vs round 0:
//  - h1s stride 80 -> 72 elems (bank stride 8 -> 4 mod 32): conflicts
//    5.24M -> 3.67M, verified R4/R5.
//  - pc passthrough moved off the prep->main critical path into gather.
// De-phasing/setprio/W2-in-regs all REVERTED: every variant (R1-R5) pushed
// the ~108-reg working set over the 128-VGPR cliff into in-loop spills.
__global__ __launch_bounds__(512, 2) void main_kernel(
    const float* __restrict__ pc, const float* __restrict__ tt, const int* __restrict__ idx,
    const float* __restrict__ bg1, const float* __restrict__ bg2, const float* __restrict__ bg3,
    const float* __restrict__ bl1, const float* __restrict__ bl2, const float* __restrict__ bl3,
    float* __restrict__ out, char* __restrict__ ws) {
    __shared__ __align__(16) char smem[100864];
    __bf16* h2f = (__bf16*)smem;               // 2 x 16384 elems (65536 B)
    __bf16* w2f = (__bf16*)(smem + 65536);     // 8192 elems (16384 B)
    __bf16* h1s = (__bf16*)(smem + 81920);     // 8 waves x [16pt][72] (18432 B)
    float*  b2s = (float*)(smem + 100352);     // 128 f32 (512 B)

    const int tid = threadIdx.x, lane = tid & 63, wave = tid >> 6;
    const int quad = lane >> 4, l15 = lane & 15;
    const int branch = blockIdx.y, frame = blockIdx.x;

    const __bf16* w1g = (const __bf16*)(ws + (branch ? WS_W1F_L : WS_W1F_G));
    const __bf16* w2g = (const __bf16*)(ws + (branch ? WS_W2F_L : WS_W2F_G));
    const __bf16* w3g = (const __bf16*)(ws + (branch ? WS_W3F_L : WS_W3F_G));
    const float* b1 = branch ? bl1 : bg1;
    const float* b2 = branch ? bl2 : bg2;
    const float* b3 = branch ? bl3 : bg3;

    // stage W2 frags + b2 into LDS
    for (int i = tid; i < 1024; i += 512) ((f32x4*)w2f)[i] = ((const f32x4*)w2g)[i];
    if (tid < 128) b2s[tid] = b2[tid];

    // resident frags: W1 (16 VGPR), W3 slice (64 VGPR)
    bf16x8 a1[4];
    #pragma unroll
    for (int mi = 0; mi < 4; ++mi) a1[mi] = *(const bf16x8*)(w1g + mi * 512 + lane * 8);
    bf16x8 aw[4][4];
    #pragma unroll
    for (int mi = 0; mi < 4; ++mi)
        #pragma unroll
        for (int ks = 0; ks < 4; ++ks)
            aw[mi][ks] = *(const bf16x8*)(w3g + (wave * 16 + mi * 4 + ks) * 512 + lane * 8);

    float b1r[4][4];
    #pragma unroll
    for (int mi = 0; mi < 4; ++mi)
        #pragma unroll
        for (int r = 0; r < 4; ++r) b1r[mi][r] = b1[mi * 16 + quad * 4 + r];

    const float tval = tt[frame];
    const f32x4 zf = {0.0f, 0.0f, 0.0f, 0.0f};
    f32x4 runmax[4];
    #pragma unroll
    for (int mi = 0; mi < 4; ++mi) runmax[mi] = (f32x4){-1e30f, -1e30f, -1e30f, -1e30f};

    const float* pcx = pc + (size_t)frame * 3 * NP;
    __bf16* hs = h1s + wave * 1152;      // private [16][72] scratch
    const int pw = wave * 16 + l15;      // this wave's point (col l15) in a macro

    // macro-0 x
    float xx = pcx[pw], xy = pcx[NP + pw], xz = pcx[2 * NP + pw];

    __syncthreads();   // w2f/b2s ready

    // ---- prologue: P1(0) -> buf 0
    {
        bf16x8 xb;
        #pragma unroll
        for (int j = 0; j < 8; ++j) xb[j] = (__bf16)0.0f;
        if (quad == 0) { xb[0] = (__bf16)xx; xb[1] = (__bf16)xy; xb[2] = (__bf16)xz; xb[3] = (__bf16)tval; }
        #pragma unroll
        for (int mi = 0; mi < 4; ++mi) {
            f32x4 c = __builtin_amdgcn_mfma_f32_16x16x32_bf16(a1[mi], xb, zf, 0, 0, 0);
            bf16x4 pk;
            #pragma unroll
            for (int r = 0; r < 4; ++r) pk[r] = (__bf16)fmaxf(c[r] + b1r[mi][r], 0.0f);
            *(bf16x4*)(hs + l15 * 72 + mi * 16 + quad * 4) = pk;
        }
        bf16x8 hbf0 = *(const bf16x8*)(hs + l15 * 72 + quad * 8);
        bf16x8 hbf1 = *(const bf16x8*)(hs + l15 * 72 + 32 + quad * 8);
        #pragma unroll
        for (int mi = 0; mi < 8; ++mi) {
            bf16x8 a20 = *(const bf16x8*)(w2f + (mi * 2) * 512 + lane * 8);
            bf16x8 a21 = *(const bf16x8*)(w2f + (mi * 2 + 1) * 512 + lane * 8);
            f32x4 c = __builtin_amdgcn_mfma_f32_16x16x32_bf16(a20, hbf0, zf, 0, 0, 0);
            c = __builtin_amdgcn_mfma_f32_16x16x32_bf16(a21, hbf1, c, 0, 0, 0);
            f32x4 bb = *(const f32x4*)(b2s + mi * 16 + quad * 4);
            bf16x4 pk;
            #pragma unroll
            for (int r = 0; r < 4; ++r) pk[r] = (__bf16)fmaxf(c[r] + bb[r], 0.0f);
            const int c0 = mi * 16 + quad * 4;
            *(bf16x4*)(h2f + ((wave * 4 + (c0 >> 5)) * 4 + ((c0 >> 3) & 3)) * 128 + l15 * 8 + (c0 & 7)) = pk;
        }
    }

    for (int m = 0; m < 32; ++m) {
        __syncthreads();   // h2f buf[m&1] ready (prologue or previous stage C)
        const __bf16* hb = h2f + (m & 1) * 16384;
        __bf16* hbn = h2f + ((m + 1) & 1) * 16384;
        const bool more = (m < 31);
        // prefetch next macro's x early (covered by >=2 ni-groups of MFMA)
        float nx = 0.f, ny = 0.f, nz = 0.f;
        if (more) {
            const int p = (m + 1) * 128 + pw;
            nx = pcx[p]; ny = pcx[NP + p]; nz = pcx[2 * NP + p];
        }
        bf16x8 hbf0, hbf1;
        bf16x8 bh0[4], bh1[4];
        #pragma unroll
        for (int ks = 0; ks < 4; ++ks) bh0[ks] = *(const bf16x8*)(hb + ks * 512 + lane * 8);
        #pragma unroll
        for (int ni = 0; ni < 8; ++ni) {
            bf16x8* cur = (ni & 1) ? bh1 : bh0;
            bf16x8* nxt = (ni & 1) ? bh0 : bh1;
            if (ni < 7) {
                #pragma unroll
                for (int ks = 0; ks < 4; ++ks)
                    nxt[ks] = *(const bf16x8*)(hb + ((ni + 1) * 4 + ks) * 512 + lane * 8);
            }
            f32x4 acc[4];
            #pragma unroll
            for (int ks = 0; ks < 4; ++ks)
                #pragma unroll
                for (int mi = 0; mi < 4; ++mi)
                    acc[mi] = __builtin_amdgcn_mfma_f32_16x16x32_bf16(
                        aw[mi][ks], cur[ks], ks ? acc[mi] : zf, 0, 0, 0);
            #pragma unroll
            for (int mi = 0; mi < 4; ++mi)
                #pragma unroll
                for (int r = 0; r < 4; ++r)
                    runmax[mi][r] = fmaxf(runmax[mi][r], acc[mi][r]);

            if (more && ni == 2) {   // P1 stage A: L1 of macro m+1, private scratch
                bf16x8 xb;
                #pragma unroll
                for (int j = 0; j < 8; ++j) xb[j] = (__bf16)0.0f;
                if (quad == 0) { xb[0] = (__bf16)nx; xb[1] = (__bf16)ny; xb[2] = (__bf16)nz; xb[3] = (__bf16)tval; }
                #pragma unroll
                for (int mi = 0; mi < 4; ++mi) {
                    f32x4 c = __builtin_amdgcn_mfma_f32_16x16x32_bf16(a1[mi], xb, zf, 0, 0, 0);
                    bf16x4 pk;
                    #pragma unroll
                    for (int r = 0; r < 4; ++r) pk[r] = (__bf16)fmaxf(c[r] + b1r[mi][r], 0.0f);
                    *(bf16x4*)(hs + l15 * 72 + mi * 16 + quad * 4) = pk;
                }
            }
            if (more && ni == 4) {   // stage B: C->B transform readback
                hbf0 = *(const bf16x8*)(hs + l15 * 72 + quad * 8);
                hbf1 = *(const bf16x8*)(hs + l15 * 72 + 32 + quad * 8);
            }
            if (more && ni == 6) {   // stage C: L2 -> write next h2f buffer
                #pragma unroll
                for (int mi = 0; mi < 8; ++mi) {
                    bf16x8 a20 = *(const bf16x8*)(w2f + (mi * 2) * 512 + lane * 8);
                    bf16x8 a21 = *(const bf16x8*)(w2f + (mi * 2 + 1) * 512 + lane * 8);
                    f32x4 c = __builtin_amdgcn_mfma_f32_16x16x32_bf16(a20, hbf0, zf, 0, 0, 0);
                    c = __builtin_amdgcn_mfma_f32_16x16x32_bf16(a21, hbf1, c, 0, 0, 0);
                    f32x4 bb = *(const f32x4*)(b2s + mi * 16 + quad * 4);
                    bf16x4 pk;
                    #pragma unroll
                    for (int r = 0; r < 4; ++r) pk[r] = (__bf16)fmaxf(c[r] + bb[r], 0.0f);
                    const int c0 = mi * 16 + quad * 4;
                    *(bf16x4*)(hbn + ((wave * 4 + (c0 >> 5)) * 4 + ((c0 >> 3) & 3)) * 128 + l15 * 8 + (c0 & 7)) = pk;
                }
            }
        }
    }

    // ---- finalize: fold 16 point-columns, bias3+relu, store/atomic
    const int g = idx[frame];
    float* gmax = (float*)(ws + WS_GMAX);
    #pragma unroll
    for (int mi = 0; mi < 4; ++mi) {
        f32x4 v = runmax[mi];
        #pragma unroll
        for (int d = 1; d < 16; d <<= 1) {
            #pragma unroll
            for (int r = 0; r < 4; ++r) v[r] = fmaxf(v[r], __shfl_xor(v[r], d));
        }
        if (l15 == 0) {
            #pragma unroll
            for (int r = 0; r < 4; ++r) {
                const int ch = wave * 64 + mi * 16 + quad * 4 + r;
                const float fv = fmaxf(v[r] + b3[ch], 0.0f);
                if (branch == 0)
                    atomicMax((unsigned*)(gmax + g * C3 + ch), __float_as_uint(fv)); // relu>=0
                else
                    out[(size_t)frame * (2 * C3) + C3 + ch] = fv;  // block owns whole frame
            }
        }
    }
}

__global__ void gather_kernel(const int* __restrict__ idx, const char* __restrict__ ws,
                              const float* __restrict__ pc, float* __restrict__ out) {
    int i = blockIdx.x * blockDim.x + threadIdx.x;   // 0..65535
    int b = i >> 9, ch = i & 511;
    const float* gmax = (const float*)(ws + WS_GMAX);
    out[b * (2 * C3) + ch] = gmax[idx[b] * C3 + ch];
    // pc passthrough (off the prep->main critical path): 393216 float4
    const f32x4* src = (const f32x4*)pc;
    f32x4* dst = (f32x4*)(out + NB * 2 * C3);
    #pragma unroll
    for (int j = 0; j < 6; ++j) dst[i + j * 65536] = src[i + j * 65536];
}

extern "C" void kernel_launch(void* const* d_in, const int* in_sizes, int n_in,
                              void* d_out, int out_size, void* d_ws, size_t ws_size,
                              hipStream_t stream) {
    const float* pc  = (const float*)d_in[0];
    const float* tt  = (const float*)d_in[1];
    const int*   idx = (const int*)d_in[2];
    const float* Wg1 = (const float*)d_in[3];  const float* bg1 = (const float*)d_in[4];
    const float* Wg2 = (const float*)d_in[5];  const float* bg2 = (const float*)d_in[6];
    const float* Wg3 = (const float*)d_in[7];  const float* bg3 = (const float*)d_in[8];
    const float* Wl1 = (const float*)d_in[9];  const float* bl1 = (const float*)d_in[10];
    const float* Wl2 = (const float*)d_in[11]; const float* bl2 = (const float*)d_in[12];
    const float* Wl3 = (const float*)d_in[13]; const float* bl3 = (const float*)d_in[14];
    float* out = (float*)d_out;
    char*  ws  = (char*)d_ws;

    // prep: weight frag layout (LDS transpose), gmax zero
    prep_kernel<<<37, 256, 0, stream>>>(Wg1, Wg2, Wg3, Wl1, Wl2, Wl3, ws);
    // main: 128 frames x 2 branches = 256 blocks = 1 per CU
    main_kernel<<<dim3(128, 2), 512, 0, stream>>>(pc, tt, idx, bg1, bg2, bg3,
                                                  bl1, bl2, bl3, out, ws);
    gather_kernel<<<256, 256, 0, stream>>>(idx, ws, pc, out);
}